// Round 14
// baseline (154.180 us; speedup 1.0000x reference)
//
#include <hip/hip_runtime.h>

#define HID 128
#define F_IN 11
#define FP 16
#define N_ACT 6
#define EPB 2048   // edges per block for k_part (= 8 * 256)
#define LMAX 6144  // k_local LDS staging capacity (edges)
#define CAP 8192   // padded bucket capacity (mean ~5000 padded)

typedef __bf16 bf16;
typedef __bf16 v8bf __attribute__((ext_vector_type(8)));
typedef float f32x4 __attribute__((ext_vector_type(4)));
typedef float v2f __attribute__((ext_vector_type(2)));

__device__ inline float lo16(unsigned u) { return __uint_as_float(u << 16); }
__device__ inline float hi16(unsigned u) { return __uint_as_float(u & 0xffff0000u); }
__device__ inline unsigned pk2(float a, float b) {
  union { bf16 h; unsigned short u; } x, y;
  x.h = (bf16)a; y.h = (bf16)b;
  return ((unsigned)y.u << 16) | x.u;
}
// fp8 e4m3 (OCP) hardware converts — selector args must be literal constants
__device__ inline v2f fp8_dec_lo(unsigned v) {
  return __builtin_amdgcn_cvt_pk_f32_fp8(v, false);
}
__device__ inline v2f fp8_dec_hi(unsigned v) {
  return __builtin_amdgcn_cvt_pk_f32_fp8(v, true);
}
__device__ inline unsigned fp8_enc2_lo(float a, float b, unsigned old) {
  return __builtin_amdgcn_cvt_pk_fp8_f32(a, b, old, false);
}
__device__ inline unsigned fp8_enc2_hi(float a, float b, unsigned old) {
  return __builtin_amdgcn_cvt_pk_fp8_f32(a, b, old, true);
}
__device__ inline unsigned char fp8_enc1(float v) {
  return (unsigned char)(__builtin_amdgcn_cvt_pk_fp8_f32(v, v, 0u, false) & 0xffu);
}

// ---------------- init: cursors, gsum, dummy rows (index N) ----------------

__global__ __launch_bounds__(256) void k_init(int* __restrict__ gcur,
                                              float* __restrict__ gsum,
                                              unsigned* __restrict__ xsN,
                                              unsigned* __restrict__ H8aN,
                                              unsigned* __restrict__ H8bN, int nbkt) {
  int t = threadIdx.x;
  if (t < nbkt) gcur[t] = t * CAP;
  if (t < HID) gsum[t] = 0.f;
  if (t < 8) xsN[t] = 0u;                       // xs row N (16 bf16)
  if (t < 32) { H8aN[t] = 0u; H8bN[t] = 0u; }   // fp8 rows N (128 fp8)
}

// ---------------- CSR build (padded-bucket counting sort; requires N < 65535) ----------------

__global__ __launch_bounds__(256) void k_part(const int* __restrict__ esrc,
                                              const int* __restrict__ edst,
                                              int* __restrict__ gcur,
                                              unsigned* __restrict__ ebuf,
                                              const float* __restrict__ W2,
                                              const float* __restrict__ W3,
                                              bf16* __restrict__ WT2,
                                              bf16* __restrict__ WT3,
                                              int E, int nbkt) {
  __shared__ int hist[256], lofs[256], lcur[256], gbase[256];
  __shared__ unsigned sbuf[EPB];
  int t = threadIdx.x;
  hist[t] = 0;
  if (blockIdx.x < 64) {   // WT[n][k] = bf16(W[k][n])
    int i = blockIdx.x * 256 + t;
    int nn = i >> 7, k = i & 127;
    WT2[i] = (bf16)W2[k * 128 + nn];
    WT3[i] = (bf16)W3[k * 128 + nn];
  }
  __syncthreads();
  int start = blockIdx.x * EPB, end = min(E, start + EPB);
  unsigned u[8];
#pragma unroll
  for (int i = 0; i < 8; ++i) {
    int e = start + t + i * 256;
    if (e < end) {
      int s = esrc[e], d = edst[e];
      u[i] = ((unsigned)d << 16) | (unsigned)s;
      atomicAdd(&hist[d >> 8], 1);
    }
  }
  __syncthreads();
  int h = hist[t];
  lofs[t] = h;
  __syncthreads();
  for (int off = 1; off < 256; off <<= 1) {
    int x = (t >= off) ? lofs[t - off] : 0;
    __syncthreads();
    lofs[t] += x;
    __syncthreads();
  }
  lcur[t] = lofs[t] - h;
  if (t < nbkt && h) gbase[t] = atomicAdd(&gcur[t], h);   // bulk reservation
  __syncthreads();
#pragma unroll
  for (int i = 0; i < 8; ++i) {
    int e = start + t + i * 256;
    if (e < end) {
      int b = (int)(u[i] >> 24);
      int p = atomicAdd(&lcur[b], 1);
      sbuf[p] = u[i];
    }
  }
  __syncthreads();
  int m = end - start;
  for (int i = t; i < m; i += 256) {
    unsigned v = sbuf[i];
    int b = (int)(v >> 24);
    int excl = lofs[b] - hist[b];
    ebuf[gbase[b] + (i - excl)] = v;
  }
}

// one workgroup per bucket (1024 threads): LDS-staged hist + scan + fill.
// Edge runs PADDED to multiples of 8 with dummy src=N (zero row).
__global__ __launch_bounds__(1024) void k_local(const unsigned* __restrict__ ebuf,
                                                const int* __restrict__ gcur,
                                                int2* __restrict__ rbe,
                                                float* __restrict__ dinv,
                                                unsigned short* __restrict__ cs,
                                                const float* __restrict__ x,
                                                bf16* __restrict__ xs, int n) {
  __shared__ int hist[256], lofs[256], cur[256], realh[256];
  __shared__ float dsh[256];
  __shared__ unsigned sb[LMAX];
  int b = blockIdx.x, t = threadIdx.x;
  int rb = b * CAP, re = gcur[b];
  int m = re - rb;
  int nbase = b << 8;
  bool fit = (m <= LMAX);
  if (t < 256) hist[t] = 0;
  __syncthreads();
  if (fit) {
    for (int i = t; i < m; i += 1024) {
      unsigned u = ebuf[rb + i];
      sb[i] = u;
      atomicAdd(&hist[(int)(u >> 16) - nbase], 1);
    }
  } else {
    for (int i = t; i < m; i += 1024)
      atomicAdd(&hist[(int)(ebuf[rb + i] >> 16) - nbase], 1);
  }
  __syncthreads();
  int h = 0, hp = 0;
  if (t < 256) {
    h = hist[t];
    realh[t] = h;
    hp = (h + 7) & ~7;       // pad to multiple of 8
    lofs[t] = hp;
  }
  __syncthreads();
  for (int off = 1; off < 256; off <<= 1) {
    int v = (t < 256 && t >= off) ? lofs[t - off] : 0;
    __syncthreads();
    if (t < 256) lofs[t] += v;
    __syncthreads();
  }
  if (t < 256) {
    int pexcl = lofs[t] - hp;
    cur[t] = rb + pexcl;
    float dv = rsqrtf((float)h + 1.0f);
    dsh[t] = dv;
    int g = nbase + t;
    if (g < n) {
      rbe[g] = make_int2(rb + pexcl, rb + pexcl + hp);
      dinv[g] = dv;
    }
  }
  __syncthreads();
  if (fit) {
    for (int i = t; i < m; i += 1024) {
      unsigned u = sb[i];
      int p = atomicAdd(&cur[(int)(u >> 16) - nbase], 1);
      cs[p] = (unsigned short)(u & 0xffffu);
    }
  } else {
    for (int i = t; i < m; i += 1024) {
      unsigned u = ebuf[rb + i];
      int p = atomicAdd(&cur[(int)(u >> 16) - nbase], 1);
      cs[p] = (unsigned short)(u & 0xffffu);
    }
  }
  __syncthreads();
  // pad each node's run [h, hp) with dummy src = n (zero row)
  if (t < 256) {
    int hh = realh[t];
    int hpp = (hh + 7) & ~7;
    int base = cur[t];  // == run start + hh after fill
    for (int i = hh; i < hpp; ++i) cs[base + (i - hh)] = (unsigned short)n;
  }
  // xs = x * dinv (bf16, padded to 16 cols) for this bucket's nodes
  for (int i = t; i < 256 * FP; i += 1024) {
    int node = nbase + (i >> 4), c = i & 15;
    if (node < n)
      xs[(size_t)node * FP + c] =
          (bf16)((c < F_IN) ? x[(size_t)node * F_IN + c] * dsh[i >> 4] : 0.f);
  }
}

// ---------------- layer 1: fused gather16 + 11->128 GEMM -> h1 (fp8) ----------------

__global__ __launch_bounds__(256) void k_layer1(const bf16* __restrict__ xs,
                                                const float* __restrict__ dinv,
                                                const int2* __restrict__ rbe,
                                                const unsigned short* __restrict__ cs,
                                                const float* __restrict__ W1,
                                                const float* __restrict__ b1,
                                                unsigned* __restrict__ H8, int n) {
  __shared__ float Ws[F_IN * HID];
  __shared__ float A1s[64][17];
  int tid = threadIdx.x;
  int n0 = blockIdx.x * 64;
  for (int i = tid; i < F_IN * HID; i += 256) Ws[i] = W1[i];
  int wave = tid >> 6, lane = tid & 63;
  int g8 = lane >> 3, c = lane & 7;
  const unsigned* xs2 = (const unsigned*)xs;
#pragma unroll
  for (int r = 0; r < 2; ++r) {
    int row = wave * 16 + r * 8 + g8;
    int node = n0 + row;
    unsigned sv = 0;
    int j = 0, jend = 0;
    float dd = 0.f;
    if (node < n) {
      sv = xs2[(size_t)node * 8 + c];
      int2 be = rbe[node];
      j = be.x; jend = be.y;
      dd = dinv[node];
    }
    float ax = lo16(sv), ay = hi16(sv);
    for (; j < jend; j += 4) {    // padded: no masking; dummies read zero row
#pragma unroll
      for (int k = 0; k < 4; ++k) {
        unsigned v = xs2[(size_t)cs[j + k] * 8 + c];
        ax += lo16(v);
        ay += hi16(v);
      }
    }
    A1s[row][c * 2] = ax * dd;
    A1s[row][c * 2 + 1] = ay * dd;
  }
  __syncthreads();
  int tc = tid & 15, tr = tid >> 4;
  float bb[8];
#pragma unroll
  for (int j = 0; j < 8; ++j) bb[j] = b1[tc * 8 + j];
#pragma unroll
  for (int i = 0; i < 4; ++i) {
    int row = tr * 4 + i;
    int node = n0 + row;
    if (node >= n) continue;
    float acc[8];
#pragma unroll
    for (int j = 0; j < 8; ++j) acc[j] = 0.f;
#pragma unroll
    for (int k = 0; k < F_IN; ++k) {
      float xk = A1s[row][k];
      const float* wr = &Ws[k * HID + tc * 8];
#pragma unroll
      for (int j = 0; j < 8; ++j) acc[j] = fmaf(xk, wr[j], acc[j]);
    }
    float dd = dinv[node];
    float o[8];
#pragma unroll
    for (int j = 0; j < 8; ++j) o[j] = fmaxf(acc[j] + bb[j], 0.f) * dd;
    unsigned w0 = 0, w1 = 0;
    w0 = fp8_enc2_lo(o[0], o[1], w0);
    w0 = fp8_enc2_hi(o[2], o[3], w0);
    w1 = fp8_enc2_lo(o[4], o[5], w1);
    w1 = fp8_enc2_hi(o[6], o[7], w1);
    ((uint2*)H8)[(size_t)node * 16 + tc] = make_uint2(w0, w1);
  }
}

// ---------------- layers 2/3: fused fp8-gather + MFMA (64-node tile, 512 thr) ----------------

// Gather: lane = (edge-slot g4 = lane>>4, 8B-chunk q = lane&15). ONE uint2 load
// instruction fetches 4 DISTINCT edges' full 128B rows (4 random rows/instr vs 1-2
// in r11-13 — attacks the measured ~15G random-rows/s invariant). Per node:
// deg/8 ping-pong iterations, then 2-round shfl_xor(16,32) reduce over edge-slot
// groups, add self row, g4==0 lanes write the swizzled LDS chunk (kc = q).
// MFMA: 4 frags/wave; B-fragments straight from global WT (L2-resident).

#define DECACC(v)                                   \
  c0 += fp8_dec_lo(v.x); c1 += fp8_dec_hi(v.x);     \
  c2 += fp8_dec_lo(v.y); c3 += fp8_dec_hi(v.y);

template <bool FINAL>
__global__ __launch_bounds__(512) void k_layer(const unsigned* __restrict__ tab,
                                               const float* __restrict__ dinv,
                                               const int2* __restrict__ rbe,
                                               const unsigned short* __restrict__ cs,
                                               const bf16* __restrict__ WT,
                                               const float* __restrict__ b,
                                               unsigned char* __restrict__ H8,
                                               float* __restrict__ gsum, int n) {
  __shared__ bf16 Asm[64 * 128];   // 16 KB, XOR-swizzled 16B chunks
  __shared__ float colacc[128];
  int tid = threadIdx.x;
  int n0 = blockIdx.x * 64;
  if (FINAL && tid < 128) colacc[tid] = 0.f;
  int wave = tid >> 6, lane = tid & 63;
  int q = lane & 15;    // 8B chunk within 128B row
  int g4 = lane >> 4;   // edge slot 0..3
  const uint2* tab2 = (const uint2*)tab;
#pragma unroll 2
  for (int r = 0; r < 8; ++r) {
    int row = wave * 8 + r;
    int node = n0 + row;
    v2f c0 = (v2f){0.f, 0.f}, c1 = (v2f){0.f, 0.f};
    v2f c2 = (v2f){0.f, 0.f}, c3 = (v2f){0.f, 0.f};
    float dd = 0.f;
    uint2 sv = make_uint2(0u, 0u);
    int j = 0, jend = 0;
    if (node < n) {
      sv = tab2[(size_t)node * 16 + q];   // self row (issued early)
      int2 be = rbe[node];
      j = be.x; jend = be.y;
      dd = dinv[node];
    }
    if (j < jend) {   // padded run: positive multiple of 8
      uint2 va = tab2[(size_t)cs[j + g4] * 16 + q];
      uint2 vb = tab2[(size_t)cs[j + 4 + g4] * 16 + q];
      j += 8;
      for (; j < jend; j += 8) {
        uint2 na = tab2[(size_t)cs[j + g4] * 16 + q];
        DECACC(va)
        va = na;
        uint2 nb = tab2[(size_t)cs[j + 4 + g4] * 16 + q];
        DECACC(vb)
        vb = nb;
      }
      DECACC(va)
      DECACC(vb)
    }
    // reduce across the 4 edge-slot groups (lane strides 16, 32)
    c0.x += __shfl_xor(c0.x, 16); c0.x += __shfl_xor(c0.x, 32);
    c0.y += __shfl_xor(c0.y, 16); c0.y += __shfl_xor(c0.y, 32);
    c1.x += __shfl_xor(c1.x, 16); c1.x += __shfl_xor(c1.x, 32);
    c1.y += __shfl_xor(c1.y, 16); c1.y += __shfl_xor(c1.y, 32);
    c2.x += __shfl_xor(c2.x, 16); c2.x += __shfl_xor(c2.x, 32);
    c2.y += __shfl_xor(c2.y, 16); c2.y += __shfl_xor(c2.y, 32);
    c3.x += __shfl_xor(c3.x, 16); c3.x += __shfl_xor(c3.x, 32);
    c3.y += __shfl_xor(c3.y, 16); c3.y += __shfl_xor(c3.y, 32);
    // self-loop contribution (added once, post-reduction) + scale
    DECACC(sv)
    if (g4 == 0) {
      uint4 w = make_uint4(pk2(c0.x * dd, c0.y * dd), pk2(c1.x * dd, c1.y * dd),
                           pk2(c2.x * dd, c2.y * dd), pk2(c3.x * dd, c3.y * dd));
      *(uint4*)((char*)Asm + row * 256 + ((q ^ (row & 7)) << 4)) = w;
    }
  }
  __syncthreads();
  // MFMA: 16x16x32 bf16; A from swizzled LDS, B (16B frags) from global WT
  int l15 = lane & 15, g = lane >> 4;
  int rg = (wave & 3) * 16;
  int cg = (wave >> 2) * 64;
  f32x4 acc[4];
#pragma unroll
  for (int f = 0; f < 4; ++f) acc[f] = (f32x4){0.f, 0.f, 0.f, 0.f};
  int arow = rg + l15;
#pragma unroll
  for (int kk = 0; kk < 4; ++kk) {
    int kc = kk * 4 + g;
    v8bf a = *(const v8bf*)((const char*)Asm + arow * 256 + ((kc ^ (arow & 7)) << 4));
#pragma unroll
    for (int f = 0; f < 4; ++f) {
      int nrow = cg + f * 16 + l15;
      v8bf bfr = *(const v8bf*)(WT + (size_t)nrow * 128 + kc * 8);
      acc[f] = __builtin_amdgcn_mfma_f32_16x16x32_bf16(a, bfr, acc[f], 0, 0, 0);
    }
  }
  int nodebase = n0 + rg + g * 4;
  if (FINAL) {
#pragma unroll
    for (int f = 0; f < 4; ++f) {
      int col = cg + f * 16 + l15;
      float bias = b[col];
      float sf = 0.f;
#pragma unroll
      for (int j = 0; j < 4; ++j) {
        int node = nodebase + j;
        if (node < n) sf += fmaxf(acc[f][j] + bias, 0.f);
      }
      atomicAdd(&colacc[col], sf);
    }
    __syncthreads();
    if (tid < 128) atomicAdd(&gsum[tid], colacc[tid]);
  } else {
    float dv[4];
#pragma unroll
    for (int j = 0; j < 4; ++j)
      dv[j] = (nodebase + j < n) ? dinv[nodebase + j] : 1.f;
#pragma unroll
    for (int f = 0; f < 4; ++f) {
      int col = cg + f * 16 + l15;
      float bias = b[col];
#pragma unroll
      for (int j = 0; j < 4; ++j) {
        int node = nodebase + j;
        if (node < n) {
          float v = fmaxf(acc[f][j] + bias, 0.f) * dv[j];
          H8[(size_t)node * 128 + col] = fp8_enc1(v);
        }
      }
    }
  }
}

#undef DECACC

// ---------------- head ----------------

__global__ __launch_bounds__(128) void k_head(const float* __restrict__ gsum,
    const float* __restrict__ Wv1, const float* __restrict__ bv1,
    const float* __restrict__ Wv2, const float* __restrict__ bv2,
    const float* __restrict__ Wa1, const float* __restrict__ ba1,
    const float* __restrict__ Wa2, const float* __restrict__ ba2,
    float* __restrict__ out, int n) {
  __shared__ float gs[HID], ha[HID], red[2], advs[N_ACT], vsh;
  int t = threadIdx.x;
  gs[t] = gsum[t] * (1.0f / (float)n);
  __syncthreads();
  float av = bv1[t], aa = ba1[t];
  for (int k = 0; k < HID; ++k) {
    float gk = gs[k];
    av = fmaf(gk, Wv1[k * HID + t], av);
    aa = fmaf(gk, Wa1[k * HID + t], aa);
  }
  float hv = fmaxf(av, 0.f);
  ha[t] = fmaxf(aa, 0.f);
  float pv = hv * Wv2[t];
#pragma unroll
  for (int o = 32; o > 0; o >>= 1) pv += __shfl_down(pv, o);
  if ((t & 63) == 0) red[t >> 6] = pv;
  __syncthreads();
  if (t == 0) vsh = red[0] + red[1] + bv2[0];
  if (t < N_ACT) {
    float adv = ba2[t];
    for (int j = 0; j < HID; ++j) adv = fmaf(ha[j], Wa2[j * N_ACT + t], adv);
    advs[t] = adv;
  }
  __syncthreads();
  if (t < N_ACT) {
    float m = 0.f;
#pragma unroll
    for (int a = 0; a < N_ACT; ++a) m += advs[a];
    m *= (1.0f / N_ACT);
    out[t] = vsh + advs[t] - m;
  }
}

// ---------------- launch ----------------

extern "C" void kernel_launch(void* const* d_in, const int* in_sizes, int n_in,
                              void* d_out, int out_size, void* d_ws, size_t ws_size,
                              hipStream_t stream) {
  const float* x   = (const float*)d_in[0];
  const int*   ei  = (const int*)d_in[1];
  const float* W1  = (const float*)d_in[2];
  const float* b1  = (const float*)d_in[3];
  const float* W2  = (const float*)d_in[4];
  const float* b2  = (const float*)d_in[5];
  const float* W3  = (const float*)d_in[6];
  const float* b3  = (const float*)d_in[7];
  const float* Wv1 = (const float*)d_in[8];
  const float* bv1 = (const float*)d_in[9];
  const float* Wv2 = (const float*)d_in[10];
  const float* bv2 = (const float*)d_in[11];
  const float* Wa1 = (const float*)d_in[12];
  const float* ba1 = (const float*)d_in[13];
  const float* Wa2 = (const float*)d_in[14];
  const float* ba2 = (const float*)d_in[15];
  float* out = (float*)d_out;

  const int N = in_sizes[0] / F_IN;   // 50000 (< 65535 required: u16 src + dummy N)
  const int E = in_sizes[1] / 2;      // 800000
  const int* esrc = ei;
  const int* edst = ei + E;
  const int nbkt = (N + 255) >> 8;    // 196
  const int gE = (E + EPB - 1) / EPB;

  char* p = (char*)d_ws;
  auto alloc = [&](size_t bytes) {
    void* r = (void*)p;
    p += (bytes + 1023) & ~(size_t)1023;
    return r;
  };
  unsigned* ebuf   = (unsigned*)alloc((size_t)nbkt * CAP * 4);     // padded buckets
  int*   gcur      = (int*)alloc((size_t)nbkt * 4);
  int2*  rbe       = (int2*)alloc((size_t)N * 8);
  float* dinv      = (float*)alloc((size_t)N * 4);
  unsigned short* cs = (unsigned short*)alloc((size_t)nbkt * CAP * 2);
  bf16*  xs        = (bf16*)alloc((size_t)(N + 1) * FP * 2);
  bf16*  WT2       = (bf16*)alloc(128 * 128 * 2);
  bf16*  WT3       = (bf16*)alloc(128 * 128 * 2);
  unsigned* H8a    = (unsigned*)alloc((size_t)(N + 1) * 128);      // h1 fp8 (+zero row)
  unsigned* H8b    = (unsigned*)alloc((size_t)(N + 1) * 128);      // h2 fp8 (+zero row)
  float* gsum      = (float*)alloc(HID * 4);

  // init (cursors, gsum, dummy zero rows at index N)
  k_init<<<1, 256, 0, stream>>>(gcur, gsum, (unsigned*)(xs + (size_t)N * FP),
                                H8a + (size_t)N * 32, H8b + (size_t)N * 32, nbkt);
  k_part<<<gE, 256, 0, stream>>>(esrc, edst, gcur, ebuf, W2, W3, WT2, WT3, E, nbkt);
  k_local<<<nbkt, 1024, 0, stream>>>(ebuf, gcur, rbe, dinv, cs, x, xs, N);

  // layer 1 (fused gather16 + GEMM -> fp8 h1)
  k_layer1<<<(N + 63) / 64, 256, 0, stream>>>(xs, dinv, rbe, cs, W1, b1, H8a, N);

  // layers 2/3: fused fp8 gather (4 rows/instr) + MFMA GEMM (64-node tiles)
  int gL = (N + 63) / 64;
  k_layer<false><<<gL, 512, 0, stream>>>(H8a, dinv, rbe, cs, WT2, b2,
                                         (unsigned char*)H8b, gsum, N);
  k_layer<true><<<gL, 512, 0, stream>>>(H8b, dinv, rbe, cs, WT3, b3,
                                        (unsigned char*)nullptr, gsum, N);

  // head
  k_head<<<1, 128, 0, stream>>>(gsum, Wv1, bv1, Wv2, bv2, Wa1, ba1, Wa2, ba2, out, N);
}

// Round 15
// 146.409 us; speedup vs baseline: 1.0531x; 1.0531x over previous
//
#include <hip/hip_runtime.h>

#define HID 128
#define F_IN 11
#define FP 16
#define N_ACT 6
#define EPB 2048   // edges per block for k_part (= 8 * 256)
#define LMAX 6144  // k_local LDS staging capacity (edges)
#define CAP 8192   // padded bucket capacity (mean 4096 real, ~5900 padded)

typedef __bf16 bf16;
typedef __bf16 v8bf __attribute__((ext_vector_type(8)));
typedef float f32x4 __attribute__((ext_vector_type(4)));
typedef float v2f __attribute__((ext_vector_type(2)));

__device__ inline float lo16(unsigned u) { return __uint_as_float(u << 16); }
__device__ inline float hi16(unsigned u) { return __uint_as_float(u & 0xffff0000u); }
__device__ inline unsigned pk2(float a, float b) {
  union { bf16 h; unsigned short u; } x, y;
  x.h = (bf16)a; y.h = (bf16)b;
  return ((unsigned)y.u << 16) | x.u;
}
// fp8 e4m3 (OCP) hardware converts — selector args must be literal constants
__device__ inline v2f fp8_dec_lo(unsigned v) {
  return __builtin_amdgcn_cvt_pk_f32_fp8(v, false);
}
__device__ inline v2f fp8_dec_hi(unsigned v) {
  return __builtin_amdgcn_cvt_pk_f32_fp8(v, true);
}
__device__ inline unsigned fp8_enc2_lo(float a, float b, unsigned old) {
  return __builtin_amdgcn_cvt_pk_fp8_f32(a, b, old, false);
}
__device__ inline unsigned fp8_enc2_hi(float a, float b, unsigned old) {
  return __builtin_amdgcn_cvt_pk_fp8_f32(a, b, old, true);
}
__device__ inline unsigned char fp8_enc1(float v) {
  return (unsigned char)(__builtin_amdgcn_cvt_pk_fp8_f32(v, v, 0u, false) & 0xffu);
}

// ---------------- init: cursors, gsum, dummy rows (index N) ----------------

__global__ __launch_bounds__(256) void k_init(int* __restrict__ gcur,
                                              float* __restrict__ gsum,
                                              unsigned* __restrict__ xsN,
                                              unsigned* __restrict__ H8aN,
                                              unsigned* __restrict__ H8bN, int nbkt) {
  int t = threadIdx.x;
  if (t < nbkt) gcur[t] = t * CAP;
  if (t < HID) gsum[t] = 0.f;
  if (t < 8) xsN[t] = 0u;                       // xs row N (16 bf16)
  if (t < 32) { H8aN[t] = 0u; H8bN[t] = 0u; }   // fp8 rows N (128 fp8)
}

// ---------------- CSR build (padded-bucket counting sort; requires N < 65535) ----------------

// block-local sort by bucket + bulk reservation into padded regions + contiguous run writes.
// blocks 0..63 also produce the bf16 weight transposes.
__global__ __launch_bounds__(256) void k_part(const int* __restrict__ esrc,
                                              const int* __restrict__ edst,
                                              int* __restrict__ gcur,
                                              unsigned* __restrict__ ebuf,
                                              const float* __restrict__ W2,
                                              const float* __restrict__ W3,
                                              bf16* __restrict__ WT2,
                                              bf16* __restrict__ WT3,
                                              int E, int nbkt) {
  __shared__ int hist[256], lofs[256], lcur[256], gbase[256];
  __shared__ unsigned sbuf[EPB];
  int t = threadIdx.x;
  hist[t] = 0;
  if (blockIdx.x < 64) {   // WT[n][k] = bf16(W[k][n])
    int i = blockIdx.x * 256 + t;
    int nn = i >> 7, k = i & 127;
    WT2[i] = (bf16)W2[k * 128 + nn];
    WT3[i] = (bf16)W3[k * 128 + nn];
  }
  __syncthreads();
  int start = blockIdx.x * EPB, end = min(E, start + EPB);
  unsigned u[8];
#pragma unroll
  for (int i = 0; i < 8; ++i) {
    int e = start + t + i * 256;
    if (e < end) {
      int s = esrc[e], d = edst[e];
      u[i] = ((unsigned)d << 16) | (unsigned)s;
      atomicAdd(&hist[d >> 8], 1);
    }
  }
  __syncthreads();
  int h = hist[t];
  lofs[t] = h;
  __syncthreads();
  for (int off = 1; off < 256; off <<= 1) {
    int x = (t >= off) ? lofs[t - off] : 0;
    __syncthreads();
    lofs[t] += x;
    __syncthreads();
  }
  lcur[t] = lofs[t] - h;
  if (t < nbkt && h) gbase[t] = atomicAdd(&gcur[t], h);   // bulk reservation
  __syncthreads();
#pragma unroll
  for (int i = 0; i < 8; ++i) {
    int e = start + t + i * 256;
    if (e < end) {
      int b = (int)(u[i] >> 24);
      int p = atomicAdd(&lcur[b], 1);
      sbuf[p] = u[i];
    }
  }
  __syncthreads();
  int m = end - start;
  for (int i = t; i < m; i += 256) {
    unsigned v = sbuf[i];
    int b = (int)(v >> 24);
    int excl = lofs[b] - hist[b];
    ebuf[gbase[b] + (i - excl)] = v;
  }
}

// one workgroup per bucket (1024 threads): LDS-staged hist + scan + fill.
// Edge runs PADDED to multiples of 16 with dummy src=N (zero row). Writes rbe (padded
// begin/end), dinv, cs(ushort), and xs (= x*dinv bf16 padded to 16 cols).
__global__ __launch_bounds__(1024) void k_local(const unsigned* __restrict__ ebuf,
                                                const int* __restrict__ gcur,
                                                int2* __restrict__ rbe,
                                                float* __restrict__ dinv,
                                                unsigned short* __restrict__ cs,
                                                const float* __restrict__ x,
                                                bf16* __restrict__ xs, int n) {
  __shared__ int hist[256], lofs[256], cur[256], realh[256];
  __shared__ float dsh[256];
  __shared__ unsigned sb[LMAX];
  int b = blockIdx.x, t = threadIdx.x;
  int rb = b * CAP, re = gcur[b];
  int m = re - rb;
  int nbase = b << 8;
  bool fit = (m <= LMAX);
  if (t < 256) hist[t] = 0;
  __syncthreads();
  if (fit) {
    for (int i = t; i < m; i += 1024) {
      unsigned u = ebuf[rb + i];
      sb[i] = u;
      atomicAdd(&hist[(int)(u >> 16) - nbase], 1);
    }
  } else {
    for (int i = t; i < m; i += 1024)
      atomicAdd(&hist[(int)(ebuf[rb + i] >> 16) - nbase], 1);
  }
  __syncthreads();
  int h = 0, hp = 0;
  if (t < 256) {
    h = hist[t];
    realh[t] = h;
    hp = (h + 15) & ~15;       // pad to multiple of 16
    lofs[t] = hp;
  }
  __syncthreads();
  for (int off = 1; off < 256; off <<= 1) {
    int v = (t < 256 && t >= off) ? lofs[t - off] : 0;
    __syncthreads();
    if (t < 256) lofs[t] += v;
    __syncthreads();
  }
  if (t < 256) {
    int pexcl = lofs[t] - hp;
    cur[t] = rb + pexcl;
    float dv = rsqrtf((float)h + 1.0f);
    dsh[t] = dv;
    int g = nbase + t;
    if (g < n) {
      rbe[g] = make_int2(rb + pexcl, rb + pexcl + hp);
      dinv[g] = dv;
    }
  }
  __syncthreads();
  if (fit) {
    for (int i = t; i < m; i += 1024) {
      unsigned u = sb[i];
      int p = atomicAdd(&cur[(int)(u >> 16) - nbase], 1);
      cs[p] = (unsigned short)(u & 0xffffu);
    }
  } else {
    for (int i = t; i < m; i += 1024) {
      unsigned u = ebuf[rb + i];
      int p = atomicAdd(&cur[(int)(u >> 16) - nbase], 1);
      cs[p] = (unsigned short)(u & 0xffffu);
    }
  }
  __syncthreads();
  // pad each node's run [h, hp) with dummy src = n (zero row)
  if (t < 256) {
    int hh = realh[t];
    int hpp = (hh + 15) & ~15;
    int base = cur[t];  // == run start + hh after fill
    for (int i = hh; i < hpp; ++i) cs[base + (i - hh)] = (unsigned short)n;
  }
  // xs = x * dinv (bf16, padded to 16 cols) for this bucket's nodes
  for (int i = t; i < 256 * FP; i += 1024) {
    int node = nbase + (i >> 4), c = i & 15;
    if (node < n)
      xs[(size_t)node * FP + c] =
          (bf16)((c < F_IN) ? x[(size_t)node * F_IN + c] * dsh[i >> 4] : 0.f);
  }
}

// ---------------- layer 1: fused gather16 + 11->128 GEMM -> h1 (fp8) ----------------

__global__ __launch_bounds__(256) void k_layer1(const bf16* __restrict__ xs,
                                                const float* __restrict__ dinv,
                                                const int2* __restrict__ rbe,
                                                const unsigned short* __restrict__ cs,
                                                const float* __restrict__ W1,
                                                const float* __restrict__ b1,
                                                unsigned* __restrict__ H8, int n) {
  __shared__ float Ws[F_IN * HID];
  __shared__ float A1s[64][17];
  int tid = threadIdx.x;
  int n0 = blockIdx.x * 64;
  for (int i = tid; i < F_IN * HID; i += 256) Ws[i] = W1[i];
  int wave = tid >> 6, lane = tid & 63;
  int g8 = lane >> 3, c = lane & 7;
  const unsigned* xs2 = (const unsigned*)xs;
#pragma unroll
  for (int r = 0; r < 2; ++r) {
    int row = wave * 16 + r * 8 + g8;
    int node = n0 + row;
    unsigned sv = 0;
    int j = 0, jend = 0;
    float dd = 0.f;
    if (node < n) {
      sv = xs2[(size_t)node * 8 + c];
      int2 be = rbe[node];
      j = be.x; jend = be.y;
      dd = dinv[node];
    }
    float ax = lo16(sv), ay = hi16(sv);
    for (; j < jend; j += 4) {    // padded: no masking; dummies read zero row
#pragma unroll
      for (int k = 0; k < 4; ++k) {
        unsigned v = xs2[(size_t)cs[j + k] * 8 + c];
        ax += lo16(v);
        ay += hi16(v);
      }
    }
    A1s[row][c * 2] = ax * dd;
    A1s[row][c * 2 + 1] = ay * dd;
  }
  __syncthreads();
  int tc = tid & 15, tr = tid >> 4;
  float bb[8];
#pragma unroll
  for (int j = 0; j < 8; ++j) bb[j] = b1[tc * 8 + j];
#pragma unroll
  for (int i = 0; i < 4; ++i) {
    int row = tr * 4 + i;
    int node = n0 + row;
    if (node >= n) continue;
    float acc[8];
#pragma unroll
    for (int j = 0; j < 8; ++j) acc[j] = 0.f;
#pragma unroll
    for (int k = 0; k < F_IN; ++k) {
      float xk = A1s[row][k];
      const float* wr = &Ws[k * HID + tc * 8];
#pragma unroll
      for (int j = 0; j < 8; ++j) acc[j] = fmaf(xk, wr[j], acc[j]);
    }
    float dd = dinv[node];
    float o[8];
#pragma unroll
    for (int j = 0; j < 8; ++j) o[j] = fmaxf(acc[j] + bb[j], 0.f) * dd;
    unsigned w0 = 0, w1 = 0;
    w0 = fp8_enc2_lo(o[0], o[1], w0);
    w0 = fp8_enc2_hi(o[2], o[3], w0);
    w1 = fp8_enc2_lo(o[4], o[5], w1);
    w1 = fp8_enc2_hi(o[6], o[7], w1);
    ((uint2*)H8)[(size_t)node * 16 + tc] = make_uint2(w0, w1);
  }
}

// ---------------- layers 2/3: fused fp8-gather + MFMA (32-node tile, 512 thr) ----------------

// Gather: 8 waves x 4 nodes (2 rounds of node-pairs; 32 lanes/node = full 128B row).
// cs prefetched as uint4 (8 indices/load); 16 tab loads per batch; packed adds.
// MFMA: 2 frags/wave; B-fragments straight from global WT (L2-resident).
template <bool FINAL>
__global__ __launch_bounds__(512) void k_layer(const unsigned* __restrict__ tab,
                                               const float* __restrict__ dinv,
                                               const int2* __restrict__ rbe,
                                               const unsigned short* __restrict__ cs,
                                               const bf16* __restrict__ WT,
                                               const float* __restrict__ b,
                                               unsigned char* __restrict__ H8,
                                               float* __restrict__ gsum, int n) {
  __shared__ bf16 Asm[32 * 128];   // 8 KB, XOR-swizzled 16B chunks
  __shared__ float colacc[128];
  int tid = threadIdx.x;
  int n0 = blockIdx.x * 32;
  if (FINAL && tid < 128) colacc[tid] = 0.f;
  int wave = tid >> 6, lane = tid & 63;
  int sub = lane >> 5;        // node within pair
  int c = lane & 31;          // u32 col (4 fp8) within 128B row
#pragma unroll
  for (int r = 0; r < 2; ++r) {
    int row = wave * 4 + r * 2 + sub;
    int node = n0 + row;
    v2f acc01 = (v2f){0.f, 0.f}, acc23 = (v2f){0.f, 0.f};
    float dd = 0.f;
    int j = 0, jend = 0;
    if (node < n) {
      unsigned sv = tab[(size_t)node * 32 + c];
      acc01 = fp8_dec_lo(sv);
      acc23 = fp8_dec_hi(sv);
      int2 be = rbe[node];
      j = be.x; jend = be.y;
      dd = dinv[node];
    }
    for (; j < jend; j += 16) {   // padded: full batches, dummies hit hot zero row
      uint4 cv0 = *(const uint4*)(cs + j);
      uint4 cv1 = *(const uint4*)(cs + j + 8);
      unsigned sx[16];
      sx[0] = cv0.x & 0xffffu;  sx[1] = cv0.x >> 16;
      sx[2] = cv0.y & 0xffffu;  sx[3] = cv0.y >> 16;
      sx[4] = cv0.z & 0xffffu;  sx[5] = cv0.z >> 16;
      sx[6] = cv0.w & 0xffffu;  sx[7] = cv0.w >> 16;
      sx[8] = cv1.x & 0xffffu;  sx[9] = cv1.x >> 16;
      sx[10] = cv1.y & 0xffffu; sx[11] = cv1.y >> 16;
      sx[12] = cv1.z & 0xffffu; sx[13] = cv1.z >> 16;
      sx[14] = cv1.w & 0xffffu; sx[15] = cv1.w >> 16;
      unsigned vv[16];
#pragma unroll
      for (int k = 0; k < 16; ++k) vv[k] = tab[(size_t)sx[k] * 32 + c];
#pragma unroll
      for (int k = 0; k < 16; ++k) {
        acc01 += fp8_dec_lo(vv[k]);
        acc23 += fp8_dec_hi(vv[k]);
      }
    }
    int kc = c >> 1, half = c & 1;
    uint2 w = make_uint2(pk2(acc01.x * dd, acc01.y * dd),
                         pk2(acc23.x * dd, acc23.y * dd));
    *(uint2*)((char*)Asm + row * 256 + ((kc ^ (row & 7)) << 4) + (half << 3)) = w;
  }
  __syncthreads();
  // MFMA: 16x16x32 bf16; A from swizzled LDS, B (16B frags) from global WT
  int l15 = lane & 15, g = lane >> 4;
  int rg = (wave & 1) * 16;
  int cbase = (wave >> 1) * 32;
  f32x4 acc[2];
#pragma unroll
  for (int f = 0; f < 2; ++f) acc[f] = (f32x4){0.f, 0.f, 0.f, 0.f};
  int arow = rg + l15;
#pragma unroll
  for (int kk = 0; kk < 4; ++kk) {
    int kc = kk * 4 + g;
    v8bf a = *(const v8bf*)((const char*)Asm + arow * 256 + ((kc ^ (arow & 7)) << 4));
#pragma unroll
    for (int f = 0; f < 2; ++f) {
      int nrow = cbase + f * 16 + l15;
      v8bf bfr = *(const v8bf*)(WT + (size_t)nrow * 128 + kc * 8);
      acc[f] = __builtin_amdgcn_mfma_f32_16x16x32_bf16(a, bfr, acc[f], 0, 0, 0);
    }
  }
  int nodebase = n0 + rg + g * 4;
  if (FINAL) {
#pragma unroll
    for (int f = 0; f < 2; ++f) {
      int col = cbase + f * 16 + l15;
      float bias = b[col];
      float sf = 0.f;
#pragma unroll
      for (int j = 0; j < 4; ++j) {
        int node = nodebase + j;
        if (node < n) sf += fmaxf(acc[f][j] + bias, 0.f);
      }
      atomicAdd(&colacc[col], sf);
    }
    __syncthreads();
    if (tid < 128) atomicAdd(&gsum[tid], colacc[tid]);
  } else {
    float dv[4];
#pragma unroll
    for (int j = 0; j < 4; ++j)
      dv[j] = (nodebase + j < n) ? dinv[nodebase + j] : 1.f;
#pragma unroll
    for (int f = 0; f < 2; ++f) {
      int col = cbase + f * 16 + l15;
      float bias = b[col];
#pragma unroll
      for (int j = 0; j < 4; ++j) {
        int node = nodebase + j;
        if (node < n) {
          float v = fmaxf(acc[f][j] + bias, 0.f) * dv[j];
          H8[(size_t)node * 128 + col] = fp8_enc1(v);
        }
      }
    }
  }
}

// ---------------- head ----------------

__global__ __launch_bounds__(128) void k_head(const float* __restrict__ gsum,
    const float* __restrict__ Wv1, const float* __restrict__ bv1,
    const float* __restrict__ Wv2, const float* __restrict__ bv2,
    const float* __restrict__ Wa1, const float* __restrict__ ba1,
    const float* __restrict__ Wa2, const float* __restrict__ ba2,
    float* __restrict__ out, int n) {
  __shared__ float gs[HID], ha[HID], red[2], advs[N_ACT], vsh;
  int t = threadIdx.x;
  gs[t] = gsum[t] * (1.0f / (float)n);
  __syncthreads();
  float av = bv1[t], aa = ba1[t];
  for (int k = 0; k < HID; ++k) {
    float gk = gs[k];
    av = fmaf(gk, Wv1[k * HID + t], av);
    aa = fmaf(gk, Wa1[k * HID + t], aa);
  }
  float hv = fmaxf(av, 0.f);
  ha[t] = fmaxf(aa, 0.f);
  float pv = hv * Wv2[t];
#pragma unroll
  for (int o = 32; o > 0; o >>= 1) pv += __shfl_down(pv, o);
  if ((t & 63) == 0) red[t >> 6] = pv;
  __syncthreads();
  if (t == 0) vsh = red[0] + red[1] + bv2[0];
  if (t < N_ACT) {
    float adv = ba2[t];
    for (int j = 0; j < HID; ++j) adv = fmaf(ha[j], Wa2[j * N_ACT + t], adv);
    advs[t] = adv;
  }
  __syncthreads();
  if (t < N_ACT) {
    float m = 0.f;
#pragma unroll
    for (int a = 0; a < N_ACT; ++a) m += advs[a];
    m *= (1.0f / N_ACT);
    out[t] = vsh + advs[t] - m;
  }
}

// ---------------- launch ----------------

extern "C" void kernel_launch(void* const* d_in, const int* in_sizes, int n_in,
                              void* d_out, int out_size, void* d_ws, size_t ws_size,
                              hipStream_t stream) {
  const float* x   = (const float*)d_in[0];
  const int*   ei  = (const int*)d_in[1];
  const float* W1  = (const float*)d_in[2];
  const float* b1  = (const float*)d_in[3];
  const float* W2  = (const float*)d_in[4];
  const float* b2  = (const float*)d_in[5];
  const float* W3  = (const float*)d_in[6];
  const float* b3  = (const float*)d_in[7];
  const float* Wv1 = (const float*)d_in[8];
  const float* bv1 = (const float*)d_in[9];
  const float* Wv2 = (const float*)d_in[10];
  const float* bv2 = (const float*)d_in[11];
  const float* Wa1 = (const float*)d_in[12];
  const float* ba1 = (const float*)d_in[13];
  const float* Wa2 = (const float*)d_in[14];
  const float* ba2 = (const float*)d_in[15];
  float* out = (float*)d_out;

  const int N = in_sizes[0] / F_IN;   // 50000 (< 65535 required: u16 src + dummy N)
  const int E = in_sizes[1] / 2;      // 800000
  const int* esrc = ei;
  const int* edst = ei + E;
  const int nbkt = (N + 255) >> 8;    // 196
  const int gE = (E + EPB - 1) / EPB;

  char* p = (char*)d_ws;
  auto alloc = [&](size_t bytes) {
    void* r = (void*)p;
    p += (bytes + 1023) & ~(size_t)1023;
    return r;
  };
  unsigned* ebuf   = (unsigned*)alloc((size_t)nbkt * CAP * 4);     // padded buckets
  int*   gcur      = (int*)alloc((size_t)nbkt * 4);
  int2*  rbe       = (int2*)alloc((size_t)N * 8);
  float* dinv      = (float*)alloc((size_t)N * 4);
  unsigned short* cs = (unsigned short*)alloc((size_t)nbkt * CAP * 2);
  bf16*  xs        = (bf16*)alloc((size_t)(N + 1) * FP * 2);
  bf16*  WT2       = (bf16*)alloc(128 * 128 * 2);
  bf16*  WT3       = (bf16*)alloc(128 * 128 * 2);
  unsigned* H8a    = (unsigned*)alloc((size_t)(N + 1) * 128);      // h1 fp8 (+zero row)
  unsigned* H8b    = (unsigned*)alloc((size_t)(N + 1) * 128);      // h2 fp8 (+zero row)
  float* gsum      = (float*)alloc(HID * 4);

  // init (cursors, gsum, dummy zero rows at index N)
  k_init<<<1, 256, 0, stream>>>(gcur, gsum, (unsigned*)(xs + (size_t)N * FP),
                                H8a + (size_t)N * 32, H8b + (size_t)N * 32, nbkt);
  k_part<<<gE, 256, 0, stream>>>(esrc, edst, gcur, ebuf, W2, W3, WT2, WT3, E, nbkt);
  k_local<<<nbkt, 1024, 0, stream>>>(ebuf, gcur, rbe, dinv, cs, x, xs, N);

  // layer 1 (fused gather16 + GEMM -> fp8 h1)
  k_layer1<<<(N + 63) / 64, 256, 0, stream>>>(xs, dinv, rbe, cs, W1, b1, H8a, N);

  // layers 2/3: fused fp8 gather + MFMA GEMM (32-node tiles)
  int gL = (N + 31) / 32;
  k_layer<false><<<gL, 512, 0, stream>>>(H8a, dinv, rbe, cs, WT2, b2,
                                         (unsigned char*)H8b, gsum, N);
  k_layer<true><<<gL, 512, 0, stream>>>(H8b, dinv, rbe, cs, WT3, b3,
                                        (unsigned char*)nullptr, gsum, N);

  // head
  k_head<<<1, 128, 0, stream>>>(gsum, Wv1, bv1, Wv2, bv2, Wa1, ba1, Wa2, ba2, out, N);
}